// Round 6
// baseline (154.765 us; speedup 1.0000x reference)
//
#include <hip/hip_runtime.h>
#include <math.h>

#define Bb 4
#define Rr 4
#define Nn 256
#define Ee 64
#define LAMDA 0.5f
#define EPSf 1e-6f

typedef float floatx4 __attribute__((ext_vector_type(4)));

// ---------------- K1: Q = n_emb @ Wq.T, K = n_emb @ Wk.T ----------------
__global__ __launch_bounds__(64) void qk_proj(
    const float* __restrict__ n_emb, const float* __restrict__ Wq,
    const float* __restrict__ Wk, float* __restrict__ Qo, float* __restrict__ Ko)
{
    int bn = blockIdx.x;        // b*N + n
    int e  = threadIdx.x;       // 0..63
    __shared__ float nrow[Ee];
    nrow[e] = n_emb[bn * Ee + e];
    __syncthreads();
    const float* wq = Wq + e * Ee;
    const float* wk = Wk + e * Ee;
    float q = 0.f, k = 0.f;
#pragma unroll
    for (int f = 0; f < Ee; ++f) {
        float nv = nrow[f];
        q += nv * wq[f];
        k += nv * wk[f];
    }
    Qo[bn * Ee + e] = q;
    Ko[bn * Ee + e] = k;
}

// ---------------- block-wide sum over 256 threads ----------------
__device__ __forceinline__ float block_sum256(float v, float* s_red) {
#pragma unroll
    for (int m = 32; m >= 1; m >>= 1) v += __shfl_xor(v, m);
    int wid  = threadIdx.x >> 6;
    int lane = threadIdx.x & 63;
    if (lane == 0) s_red[wid] = v;
    __syncthreads();
    float tot = s_red[0] + s_red[1] + s_red[2] + s_red[3];
    __syncthreads();
    return tot;
}

// ---------------- K2: the heavy fused kernel ----------------
// One block per (b, r, i) row: 4096 blocks x 256 threads.
// - ori is computed IN-KERNEL: thread j does dot(Q[b,i], K[b,j])/4096 from
//   L2/L3-resident Q,K (256 KB per batch) — kills the ori_kernel dispatch
//   and its workspace round-trip.
// - h/r/t (805 MB, read-once) and both masks (8 MB, read-once) use
//   NON-TEMPORAL loads: stream past L3 retention instead of competing
//   for the hit path (the R5 lever: mixed L3/HBM path capped at ~4 TB/s,
//   pure HBM stream runs ~6.3-7 TB/s).
// - Phase-1 loads coalesced: step v, thread t reads float4 #(v*256+t),
//   wave covers 1 KB contiguous; column jcol = v*16 + (t>>4) reduced by a
//   16-lane shfl tree. Low VGPR -> full residency for latency hiding.
__global__ __launch_bounds__(256) void raa_kernel(
    const float* __restrict__ h_adj, const float* __restrict__ r_adj,
    const float* __restrict__ t_adj, const float* __restrict__ mask_r,
    const float* __restrict__ mask_u, const float* __restrict__ Q,
    const float* __restrict__ K, float* __restrict__ out)
{
    const int blk = blockIdx.x;            // (b*R + r)*N + i
    const int b   = blk / (Rr * Nn);
    const int i   = blk % Nn;
    const int t   = threadIdx.x;

    const int rowbase4 = blk * (Nn * Ee / 4);   // float4 index, < 2^24
    const floatx4* __restrict__ hp = (const floatx4*)h_adj + rowbase4;
    const floatx4* __restrict__ rp = (const floatx4*)r_adj + rowbase4;
    const floatx4* __restrict__ tp = (const floatx4*)t_adj + rowbase4;

    __shared__ floatx4 s_q4[Ee / 4];
    __shared__ float   s_pla[Nn];
    __shared__ float   s_red[4];

    if (t < Ee / 4) s_q4[t] = ((const floatx4*)(Q + (b * Nn + i) * Ee))[t];

    // Hoisted read-once scalars (non-temporal): latency hides under phase 1.
    const int j     = t;
    const int mbase = blk * Nn;
    const float mr  = __builtin_nontemporal_load(mask_r + mbase + j);
    const float mu  = __builtin_nontemporal_load(mask_u + mbase + j);

    __syncthreads();

    // ori[b,i,j] = dot(Q[b,i], K[b,j]) / 4096   (Q row broadcast from LDS,
    // K rows are L2/L3 hits — 256 KB per batch, reused by 1024 blocks)
    const floatx4* __restrict__ kp = (const floatx4*)(K + (b * Nn + j) * Ee);
    float o = 0.f;
#pragma unroll
    for (int u = 0; u < Ee / 4; ++u) {
        floatx4 kv = kp[u];
        floatx4 qv = s_q4[u];
        o += qv[0] * kv[0] + qv[1] * kv[1] + qv[2] * kv[2] + qv[3] * kv[3];
    }
    o *= (1.0f / 4096.0f);

    // Phase 1: pla_scores[jcol] = || h + r - t ||_2 over E=64
#pragma unroll
    for (int v = 0; v < 16; ++v) {
        int idx = v * 256 + t;
        floatx4 hv = __builtin_nontemporal_load(hp + idx);
        floatx4 rv = __builtin_nontemporal_load(rp + idx);
        floatx4 tv = __builtin_nontemporal_load(tp + idx);
        float dx = hv[0] + rv[0] - tv[0];
        float dy = hv[1] + rv[1] - tv[1];
        float dz = hv[2] + rv[2] - tv[2];
        float dw = hv[3] + rv[3] - tv[3];
        float acc = dx * dx + dy * dy + dz * dz + dw * dw;
        acc += __shfl_xor(acc, 1);
        acc += __shfl_xor(acc, 2);
        acc += __shfl_xor(acc, 4);
        acc += __shfl_xor(acc, 8);
        if ((t & 15) == 0) s_pla[v * 16 + (t >> 4)] = sqrtf(acc);
    }
    __syncthreads();

    // Phase 2: masked softmax-ish chain, thread j owns column j
    float e1 = expf(-s_pla[j]) * mr;
    float s1 = block_sum256(e1, s_red);
    float w  = e1 / (s1 + EPSf);

    float raa = o * (1.0f + LAMDA * w);

    float e2 = expf(raa) * mu;
    float s2 = block_sum256(e2, s_red);

    out[mbase + j] = e2 / (s2 + EPSf);
}

extern "C" void kernel_launch(void* const* d_in, const int* in_sizes, int n_in,
                              void* d_out, int out_size, void* d_ws, size_t ws_size,
                              hipStream_t stream) {
    const float* n_emb  = (const float*)d_in[0];
    const float* h_adj  = (const float*)d_in[1];
    const float* r_adj  = (const float*)d_in[2];
    const float* t_adj  = (const float*)d_in[3];
    const float* mask_r = (const float*)d_in[4];
    const float* mask_u = (const float*)d_in[5];
    const float* Wq     = (const float*)d_in[6];
    const float* Wk     = (const float*)d_in[7];
    float* out = (float*)d_out;

    float* ws  = (float*)d_ws;
    float* Qw  = ws;                        // B*N*E = 65536 floats
    float* Kw  = ws + Bb * Nn * Ee;         // 65536 floats

    qk_proj<<<Bb * Nn, 64, 0, stream>>>(n_emb, Wq, Wk, Qw, Kw);
    raa_kernel<<<Bb * Rr * Nn, 256, 0, stream>>>(h_adj, r_adj, t_adj,
                                                 mask_r, mask_u, Qw, Kw, out);
}

// Round 7
// 143.978 us; speedup vs baseline: 1.0749x; 1.0749x over previous
//
#include <hip/hip_runtime.h>
#include <math.h>

#define Bb 4
#define Rr 4
#define Nn 256
#define Ee 64
#define LAMDA 0.5f
#define EPSf 1e-6f

typedef float floatx4 __attribute__((ext_vector_type(4)));

// ---------------- K1: Q = n_emb @ Wq.T, K = n_emb @ Wk.T ----------------
__global__ __launch_bounds__(64) void qk_proj(
    const float* __restrict__ n_emb, const float* __restrict__ Wq,
    const float* __restrict__ Wk, float* __restrict__ Qo, float* __restrict__ Ko)
{
    int bn = blockIdx.x;        // b*N + n
    int e  = threadIdx.x;       // 0..63
    __shared__ float nrow[Ee];
    nrow[e] = n_emb[bn * Ee + e];
    __syncthreads();
    const float* wq = Wq + e * Ee;
    const float* wk = Wk + e * Ee;
    float q = 0.f, k = 0.f;
#pragma unroll
    for (int f = 0; f < Ee; ++f) {
        float nv = nrow[f];
        q += nv * wq[f];
        k += nv * wk[f];
    }
    Qo[bn * Ee + e] = q;
    Ko[bn * Ee + e] = k;
}

// ---------------- K2: ori[b,q,k] = dot(Q[b,q], K[b,k]) / 4096 ----------------
__global__ __launch_bounds__(256) void ori_kernel(
    const float* __restrict__ Q, const float* __restrict__ K,
    float* __restrict__ ori)
{
    int b = blockIdx.x / Nn;
    int q = blockIdx.x % Nn;
    int k = threadIdx.x;        // 0..255
    __shared__ float4 qs[Ee / 4];
    if (k < Ee / 4) qs[k] = ((const float4*)(Q + (b * Nn + q) * Ee))[k];
    __syncthreads();
    const float4* kp = (const float4*)(K + (b * Nn + k) * Ee);
    float acc = 0.f;
#pragma unroll
    for (int u = 0; u < Ee / 4; ++u) {
        float4 kv = kp[u];
        float4 qv = qs[u];
        acc += qv.x * kv.x + qv.y * kv.y + qv.z * kv.z + qv.w * kv.w;
    }
    ori[(b * Nn + q) * Nn + k] = acc * (1.0f / 4096.0f);
}

// ---------------- block-wide sum over 256 threads ----------------
__device__ __forceinline__ float block_sum256(float v, float* s_red) {
#pragma unroll
    for (int m = 32; m >= 1; m >>= 1) v += __shfl_xor(v, m);
    int wid  = threadIdx.x >> 6;
    int lane = threadIdx.x & 63;
    if (lane == 0) s_red[wid] = v;
    __syncthreads();
    float tot = s_red[0] + s_red[1] + s_red[2] + s_red[3];
    __syncthreads();
    return tot;
}

// ---------------- K3: the heavy fused kernel ----------------
// One block per (b, r, i) row: 4096 blocks x 256 threads.
// R5 structure (the 144.5 µs config): separate ori_kernel; low VGPR ->
// full residency; h/r/t (805 MB, read-once) via NON-TEMPORAL loads so the
// stream doesn't compete for the L3 hit path (R5's +26 µs lever; the R6
// ori-fusion regression: VGPR 76 / occ 31% / serial K reads — reverted).
// Masks also nt (read-once); ori stays cached (reused by R=4 blocks);
// out uses a non-temporal store (write-once).
__global__ __launch_bounds__(256) void raa_kernel(
    const float* __restrict__ h_adj, const float* __restrict__ r_adj,
    const float* __restrict__ t_adj, const float* __restrict__ mask_r,
    const float* __restrict__ mask_u, const float* __restrict__ ori,
    float* __restrict__ out)
{
    const int blk = blockIdx.x;            // (b*R + r)*N + i
    const int b   = blk / (Rr * Nn);
    const int i   = blk % Nn;
    const int t   = threadIdx.x;

    const int rowbase4 = blk * (Nn * Ee / 4);   // float4 index, < 2^24
    const floatx4* __restrict__ hp = (const floatx4*)h_adj + rowbase4;
    const floatx4* __restrict__ rp = (const floatx4*)r_adj + rowbase4;
    const floatx4* __restrict__ tp = (const floatx4*)t_adj + rowbase4;

    // Hoist phase-2 loads: independent of phase 1, latency hides under it.
    const int j     = t;
    const int mbase = blk * Nn;
    const float mr  = __builtin_nontemporal_load(mask_r + mbase + j);
    const float mu  = __builtin_nontemporal_load(mask_u + mbase + j);
    const float o   = ori[(b * Nn + i) * Nn + j];

    __shared__ float s_pla[Nn];
    __shared__ float s_red[4];

    // Phase 1: pla_scores[jcol] = || h + r - t ||_2 over E=64.
    // Step v: thread t reads float4 #(v*256+t) -> wave covers 1KB contiguous.
    // Column jcol = v*16 + (t>>4): 16-lane shfl tree.
#pragma unroll
    for (int v = 0; v < 16; ++v) {
        int idx = v * 256 + t;
        floatx4 hv = __builtin_nontemporal_load(hp + idx);
        floatx4 rv = __builtin_nontemporal_load(rp + idx);
        floatx4 tv = __builtin_nontemporal_load(tp + idx);
        float dx = hv[0] + rv[0] - tv[0];
        float dy = hv[1] + rv[1] - tv[1];
        float dz = hv[2] + rv[2] - tv[2];
        float dw = hv[3] + rv[3] - tv[3];
        float acc = dx * dx + dy * dy + dz * dz + dw * dw;
        acc += __shfl_xor(acc, 1);
        acc += __shfl_xor(acc, 2);
        acc += __shfl_xor(acc, 4);
        acc += __shfl_xor(acc, 8);
        if ((t & 15) == 0) s_pla[v * 16 + (t >> 4)] = sqrtf(acc);
    }
    __syncthreads();

    // Phase 2: masked softmax-ish chain, thread j owns column j
    float e1 = expf(-s_pla[j]) * mr;
    float s1 = block_sum256(e1, s_red);
    float w  = e1 / (s1 + EPSf);

    float raa = o * (1.0f + LAMDA * w);

    float e2 = expf(raa) * mu;
    float s2 = block_sum256(e2, s_red);

    __builtin_nontemporal_store(e2 / (s2 + EPSf), out + mbase + j);
}

extern "C" void kernel_launch(void* const* d_in, const int* in_sizes, int n_in,
                              void* d_out, int out_size, void* d_ws, size_t ws_size,
                              hipStream_t stream) {
    const float* n_emb  = (const float*)d_in[0];
    const float* h_adj  = (const float*)d_in[1];
    const float* r_adj  = (const float*)d_in[2];
    const float* t_adj  = (const float*)d_in[3];
    const float* mask_r = (const float*)d_in[4];
    const float* mask_u = (const float*)d_in[5];
    const float* Wq     = (const float*)d_in[6];
    const float* Wk     = (const float*)d_in[7];
    float* out = (float*)d_out;

    float* ws  = (float*)d_ws;
    float* Qw  = ws;                        // B*N*E = 65536 floats
    float* Kw  = ws + Bb * Nn * Ee;         // 65536 floats
    float* ori = ws + 2 * Bb * Nn * Ee;     // B*N*N = 262144 floats

    qk_proj<<<Bb * Nn, 64, 0, stream>>>(n_emb, Wq, Wk, Qw, Kw);
    ori_kernel<<<Bb * Nn, 256, 0, stream>>>(Qw, Kw, ori);
    raa_kernel<<<Bb * Rr * Nn, 256, 0, stream>>>(h_adj, r_adj, t_adj,
                                                 mask_r, mask_u, ori, out);
}